// Round 1
// baseline (509.213 us; speedup 1.0000x reference)
//
#include <hip/hip_runtime.h>

#define B_TOT 65536
#define S 9
#define D 20
#define H 4
#define DH 5
#define DFF 512
#define EPS 1e-5f

// ws layout (floats): WqT[400] | WkT[400] | WvT[400] | WoT[400] | W1T[512*20]
#define WS_WQT 0
#define WS_WKT 400
#define WS_WVT 800
#define WS_WOT 1200
#define WS_W1T 1600
#define WS_TOTAL (1600 + DFF * D)

__global__ void prep_kernel(const float* __restrict__ Wq, const float* __restrict__ Wk,
                            const float* __restrict__ Wv, const float* __restrict__ Wo,
                            const float* __restrict__ W1, float* __restrict__ ws) {
  int stride = gridDim.x * blockDim.x;
  for (int i = blockIdx.x * blockDim.x + threadIdx.x; i < WS_TOTAL; i += stride) {
    if (i < 1600) {
      int mi = i / 400;
      int r = i % 400;
      int j = r / 20, kk = r % 20;  // ws holds WT[j][kk] = W[kk][j]
      const float* Wsrc = (mi == 0) ? Wq : (mi == 1) ? Wk : (mi == 2) ? Wv : Wo;
      ws[i] = Wsrc[kk * 20 + j];
    } else {
      int r = i - 1600;
      int f = r / 20, kk = r % 20;  // W1T[f][kk] = W1[kk][f]
      ws[i] = W1[kk * DFF + f];
    }
  }
}

// 4-way tree dot over 20 elements; w is wave-uniform -> s_loads
__device__ __forceinline__ float dot20(const float* __restrict__ w, const float* x) {
  float p0 = w[0] * x[0], p1 = w[1] * x[1], p2 = w[2] * x[2], p3 = w[3] * x[3];
#pragma unroll
  for (int k = 4; k < 20; k += 4) {
    p0 += w[k] * x[k];
    p1 += w[k + 1] * x[k + 1];
    p2 += w[k + 2] * x[k + 2];
    p3 += w[k + 3] * x[k + 3];
  }
  return (p0 + p1) + (p2 + p3);
}

__device__ __forceinline__ float sum20(const float* a) {
  float p0 = a[0] + a[4], p1 = a[1] + a[5], p2 = a[2] + a[6], p3 = a[3] + a[7];
#pragma unroll
  for (int k = 8; k < 20; k += 4) {
    p0 += a[k]; p1 += a[k + 1]; p2 += a[k + 2]; p3 += a[k + 3];
  }
  return (p0 + p1) + (p2 + p3);
}

// block = 256 threads = 4 waves; each wave owns 7 batch elements (63 lanes, 1 row/lane)
__global__ __launch_bounds__(256) void encoder_kernel(
    const float* __restrict__ X, const float* __restrict__ ws,
    const float* __restrict__ bq, const float* __restrict__ bk,
    const float* __restrict__ bv, const float* __restrict__ bo,
    const float* __restrict__ g1, const float* __restrict__ b1,
    const float* __restrict__ W2, const float* __restrict__ g2,
    const float* __restrict__ b2, float* __restrict__ Out) {
  const float* WqT = ws + WS_WQT;
  const float* WkT = ws + WS_WKT;
  const float* WvT = ws + WS_WVT;
  const float* WoT = ws + WS_WOT;
  const float* W1T = ws + WS_W1T;

  __shared__ __align__(16) float kL[4][7][9][20];
  __shared__ __align__(16) float vL[4][7][9][20];
  __shared__ __align__(16) float mL[4][7][9][20];

  const int tid = threadIdx.x;
  const int wv = tid >> 6;
  const int lane = tid & 63;
  const int bl = lane / 9;       // 0..7 (7 == inactive lane 63)
  const int s = lane - bl * 9;   // row within batch element
  const int b = (blockIdx.x * 4 + wv) * 7 + bl;
  const bool active = (bl < 7) && (b < B_TOT);

  float x[20];
  float q[20];

  if (active) {
    const float4* xr = (const float4*)(X + (size_t)b * (S * D) + s * D);
#pragma unroll
    for (int i = 0; i < 5; ++i) {
      float4 t = xr[i];
      x[4 * i + 0] = t.x; x[4 * i + 1] = t.y; x[4 * i + 2] = t.z; x[4 * i + 3] = t.w;
    }
    // q,k,v rows; k,v go to LDS for cross-row attention
#pragma unroll
    for (int j = 0; j < 20; ++j) q[j] = dot20(WqT + 20 * j, x) + bq[j];
#pragma unroll
    for (int j = 0; j < 20; ++j) kL[wv][bl][s][j] = dot20(WkT + 20 * j, x) + bk[j];
#pragma unroll
    for (int j = 0; j < 20; ++j) vL[wv][bl][s][j] = dot20(WvT + 20 * j, x) + bv[j];
  }
  __syncthreads();

  if (active) {
    // per lane: its own query row, all 4 heads; softmax fully in-lane
#pragma unroll
    for (int h = 0; h < H; ++h) {
      float sc[S];
#pragma unroll
      for (int t = 0; t < S; ++t) {
        const float* kk = &kL[wv][bl][t][h * DH];
        float d0 = q[h * DH + 0] * kk[0] + q[h * DH + 1] * kk[1];
        float d1 = q[h * DH + 2] * kk[2] + q[h * DH + 3] * kk[3];
        sc[t] = (d0 + d1 + q[h * DH + 4] * kk[4]) * (1.0f / 3.0f);
      }
      float mx = sc[0];
#pragma unroll
      for (int t = 1; t < S; ++t) mx = fmaxf(mx, sc[t]);
      float e[S];
      float sum = 0.f;
#pragma unroll
      for (int t = 0; t < S; ++t) { e[t] = __expf(sc[t] - mx); sum += e[t]; }
      float inv = 1.0f / sum;
#pragma unroll
      for (int dh = 0; dh < DH; ++dh) {
        float c = 0.f;
#pragma unroll
        for (int t = 0; t < S; ++t) c += e[t] * vL[wv][bl][t][h * DH + dh];
        // merged linear index within [9][20] row-block == h*45 + dh*9 + s
        mL[wv][bl][0][h * 45 + dh * 9 + s] = c * inv;
      }
    }
  }
  __syncthreads();

  float y[20];
  if (active) {
    float mrow[20];
#pragma unroll
    for (int j = 0; j < 20; ++j) mrow[j] = mL[wv][bl][s][j];
    float ao[20];
#pragma unroll
    for (int d = 0; d < 20; ++d) ao[d] = dot20(WoT + 20 * d, mrow) + bo[d] + x[d];
    // LayerNorm 1
    float mean = sum20(ao) * (1.0f / 20.0f);
    float c[20];
#pragma unroll
    for (int d = 0; d < 20; ++d) c[d] = ao[d] - mean;
    float var = dot20(c, c) * (1.0f / 20.0f);
    float rs = rsqrtf(var + EPS);
#pragma unroll
    for (int d = 0; d < 20; ++d) y[d] = c[d] * rs * g1[d] + b1[d];
  }

  if (active) {
    float acc[20];
#pragma unroll
    for (int d = 0; d < 20; ++d) acc[d] = 0.f;
    for (int f = 0; f < DFF; f += 2) {
      const float* w1 = W1T + f * 20;
      float h0 = dot20(w1, y);
      float h1 = dot20(w1 + 20, y);
      h0 = fmaxf(h0, 0.f);
      h1 = fmaxf(h1, 0.f);
      const float* w2 = W2 + f * 20;
#pragma unroll
      for (int d = 0; d < 20; ++d) acc[d] += h0 * w2[d] + h1 * w2[d + 20];
    }
    // LayerNorm 2 on y + ff
    float z[20];
#pragma unroll
    for (int d = 0; d < 20; ++d) z[d] = y[d] + acc[d];
    float mean = sum20(z) * (1.0f / 20.0f);
    float c[20];
#pragma unroll
    for (int d = 0; d < 20; ++d) c[d] = z[d] - mean;
    float var = dot20(c, c) * (1.0f / 20.0f);
    float rs = rsqrtf(var + EPS);
    float o[20];
#pragma unroll
    for (int d = 0; d < 20; ++d) o[d] = c[d] * rs * g2[d] + b2[d];

    float4* op = (float4*)(Out + (size_t)b * (S * D) + s * D);
#pragma unroll
    for (int i = 0; i < 5; ++i) {
      float4 t;
      t.x = o[4 * i + 0]; t.y = o[4 * i + 1]; t.z = o[4 * i + 2]; t.w = o[4 * i + 3];
      op[i] = t;
    }
  }
}

extern "C" void kernel_launch(void* const* d_in, const int* in_sizes, int n_in,
                              void* d_out, int out_size, void* d_ws, size_t ws_size,
                              hipStream_t stream) {
  const float* X  = (const float*)d_in[0];
  const float* Wq = (const float*)d_in[1];
  const float* bq = (const float*)d_in[2];
  const float* Wk = (const float*)d_in[3];
  const float* bk = (const float*)d_in[4];
  const float* Wv = (const float*)d_in[5];
  const float* bv = (const float*)d_in[6];
  const float* Wo = (const float*)d_in[7];
  const float* bo = (const float*)d_in[8];
  const float* g1 = (const float*)d_in[9];
  const float* b1 = (const float*)d_in[10];
  const float* W1 = (const float*)d_in[11];
  const float* W2 = (const float*)d_in[12];
  const float* g2 = (const float*)d_in[13];
  const float* b2 = (const float*)d_in[14];
  float* Out = (float*)d_out;
  float* ws = (float*)d_ws;

  prep_kernel<<<24, 512, 0, stream>>>(Wq, Wk, Wv, Wo, W1, ws);

  // 4 waves/block * 7 batch elements/wave = 28 batch elements per block
  int nblocks = (B_TOT + 27) / 28;
  encoder_kernel<<<nblocks, 256, 0, stream>>>(X, ws, bq, bk, bv, bo, g1, b1,
                                              W2, g2, b2, Out);
}

// Round 2
// 374.665 us; speedup vs baseline: 1.3591x; 1.3591x over previous
//
#include <hip/hip_runtime.h>

#define B_TOT 65536
#define S 9
#define D 20
#define H 4
#define DH 5
#define DFF 512
#define EPS 1e-5f

// ws layout (floats): WqT[400] | WkT[400] | WvT[400] | WoT[400] | W1T[512*20]
#define WS_WQT 0
#define WS_WKT 400
#define WS_WVT 800
#define WS_WOT 1200
#define WS_W1T 1600
#define WS_TOTAL (1600 + DFF * D)

__global__ void prep_kernel(const float* __restrict__ Wq, const float* __restrict__ Wk,
                            const float* __restrict__ Wv, const float* __restrict__ Wo,
                            const float* __restrict__ W1, float* __restrict__ ws) {
  int stride = gridDim.x * blockDim.x;
  for (int i = blockIdx.x * blockDim.x + threadIdx.x; i < WS_TOTAL; i += stride) {
    if (i < 1600) {
      int mi = i / 400;
      int r = i % 400;
      int j = r / 20, kk = r % 20;  // ws holds WT[j][kk] = W[kk][j]
      const float* Wsrc = (mi == 0) ? Wq : (mi == 1) ? Wk : (mi == 2) ? Wv : Wo;
      ws[i] = Wsrc[kk * 20 + j];
    } else {
      int r = i - 1600;
      int f = r / 20, kk = r % 20;  // W1T[f][kk] = W1[kk][f]
      ws[i] = W1[kk * DFF + f];
    }
  }
}

// 4-way tree dot over 20 elements; w is wave-uniform -> s_loads
__device__ __forceinline__ float dot20(const float* __restrict__ w, const float* x) {
  float p0 = w[0] * x[0], p1 = w[1] * x[1], p2 = w[2] * x[2], p3 = w[3] * x[3];
#pragma unroll
  for (int k = 4; k < 20; k += 4) {
    p0 += w[k] * x[k];
    p1 += w[k + 1] * x[k + 1];
    p2 += w[k + 2] * x[k + 2];
    p3 += w[k + 3] * x[k + 3];
  }
  return (p0 + p1) + (p2 + p3);
}

__device__ __forceinline__ float sum20(const float* a) {
  float p0 = a[0] + a[4], p1 = a[1] + a[5], p2 = a[2] + a[6], p3 = a[3] + a[7];
#pragma unroll
  for (int k = 8; k < 20; k += 4) {
    p0 += a[k]; p1 += a[k + 1]; p2 += a[k + 2]; p3 += a[k + 3];
  }
  return (p0 + p1) + (p2 + p3);
}

// block = 256 threads = 4 waves; each wave owns 7 batch elements (63 lanes, 1 row/lane)
// LDS: kmL holds K during attention, then is overwritten with the merged ctx
// (transpose(0,1,3,2) quirk) after a barrier. 2 arrays * 20160 B = 40320 B ->
// 4 blocks/CU -> 16 waves/CU (50% occupancy), up from 2 blocks/CU at 60 KB.
__global__ __launch_bounds__(256, 4) void encoder_kernel(
    const float* __restrict__ X, const float* __restrict__ ws,
    const float* __restrict__ bq, const float* __restrict__ bk,
    const float* __restrict__ bv, const float* __restrict__ bo,
    const float* __restrict__ g1, const float* __restrict__ b1,
    const float* __restrict__ W2, const float* __restrict__ g2,
    const float* __restrict__ b2, float* __restrict__ Out) {
  const float* WqT = ws + WS_WQT;
  const float* WkT = ws + WS_WKT;
  const float* WvT = ws + WS_WVT;
  const float* WoT = ws + WS_WOT;
  const float* W1T = ws + WS_W1T;

  __shared__ __align__(16) float kmL[4][7][9][20];
  __shared__ __align__(16) float vL[4][7][9][20];

  const int tid = threadIdx.x;
  const int wv = tid >> 6;
  const int lane = tid & 63;
  const int bl = lane / 9;       // 0..7 (7 == inactive lane 63)
  const int s = lane - bl * 9;   // row within batch element
  const int b = (blockIdx.x * 4 + wv) * 7 + bl;
  const bool active = (bl < 7) && (b < B_TOT);

  float x[20];
  float q[20];
  float ctx[20];  // attention output (already /sum), per-lane row

  if (active) {
    const float4* xr = (const float4*)(X + (size_t)b * (S * D) + s * D);
#pragma unroll
    for (int i = 0; i < 5; ++i) {
      float4 t = xr[i];
      x[4 * i + 0] = t.x; x[4 * i + 1] = t.y; x[4 * i + 2] = t.z; x[4 * i + 3] = t.w;
    }
#pragma unroll
    for (int j = 0; j < 20; ++j) q[j] = dot20(WqT + 20 * j, x) + bq[j];
#pragma unroll
    for (int j = 0; j < 20; ++j) kmL[wv][bl][s][j] = dot20(WkT + 20 * j, x) + bk[j];
#pragma unroll
    for (int j = 0; j < 20; ++j) vL[wv][bl][s][j] = dot20(WvT + 20 * j, x) + bv[j];
  }
  __syncthreads();

  if (active) {
    // per lane: its own query row; all reads of kmL/vL happen in this phase
#pragma unroll
    for (int h = 0; h < H; ++h) {
      float sc[S];
#pragma unroll
      for (int t = 0; t < S; ++t) {
        const float* kk = &kmL[wv][bl][t][h * DH];
        float d0 = q[h * DH + 0] * kk[0] + q[h * DH + 1] * kk[1];
        float d1 = q[h * DH + 2] * kk[2] + q[h * DH + 3] * kk[3];
        sc[t] = (d0 + d1 + q[h * DH + 4] * kk[4]) * (1.0f / 3.0f);
      }
      float mx = sc[0];
#pragma unroll
      for (int t = 1; t < S; ++t) mx = fmaxf(mx, sc[t]);
      float e[S];
      float sum = 0.f;
#pragma unroll
      for (int t = 0; t < S; ++t) { e[t] = __expf(sc[t] - mx); sum += e[t]; }
      float inv = 1.0f / sum;
#pragma unroll
      for (int dh = 0; dh < DH; ++dh) {
        float c = 0.f;
#pragma unroll
        for (int t = 0; t < S; ++t) c += e[t] * vL[wv][bl][t][h * DH + dh];
        ctx[h * DH + dh] = c * inv;
      }
    }
  }
  __syncthreads();  // all kmL reads done; safe to overwrite with merged ctx

  if (active) {
    // merged linear index within [9][20] row-block == h*45 + dh*9 + s
    float* mbase = &kmL[wv][bl][0][0];
#pragma unroll
    for (int h = 0; h < H; ++h)
#pragma unroll
      for (int dh = 0; dh < DH; ++dh)
        mbase[h * 45 + dh * 9 + s] = ctx[h * DH + dh];
  }
  __syncthreads();

  float y[20];
  if (active) {
    float mrow[20];
#pragma unroll
    for (int j = 0; j < 20; ++j) mrow[j] = kmL[wv][bl][s][j];
    float ao[20];
#pragma unroll
    for (int d = 0; d < 20; ++d) ao[d] = dot20(WoT + 20 * d, mrow) + bo[d] + x[d];
    // LayerNorm 1
    float mean = sum20(ao) * (1.0f / 20.0f);
    float c[20];
#pragma unroll
    for (int d = 0; d < 20; ++d) c[d] = ao[d] - mean;
    float var = dot20(c, c) * (1.0f / 20.0f);
    float rs = rsqrtf(var + EPS);
#pragma unroll
    for (int d = 0; d < 20; ++d) y[d] = c[d] * rs * g1[d] + b1[d];
  }

  if (active) {
    float acc[20];
#pragma unroll
    for (int d = 0; d < 20; ++d) acc[d] = 0.f;
    for (int f = 0; f < DFF; f += 4) {
      const float* w1 = W1T + f * 20;
      float h0 = fmaxf(dot20(w1, y), 0.f);
      float h1 = fmaxf(dot20(w1 + 20, y), 0.f);
      float h2 = fmaxf(dot20(w1 + 40, y), 0.f);
      float h3 = fmaxf(dot20(w1 + 60, y), 0.f);
      const float* w2 = W2 + f * 20;
#pragma unroll
      for (int d = 0; d < 20; ++d)
        acc[d] += h0 * w2[d] + h1 * w2[d + 20] + h2 * w2[d + 40] + h3 * w2[d + 60];
    }
    // LayerNorm 2 on y + ff
    float z[20];
#pragma unroll
    for (int d = 0; d < 20; ++d) z[d] = y[d] + acc[d];
    float mean = sum20(z) * (1.0f / 20.0f);
    float c[20];
#pragma unroll
    for (int d = 0; d < 20; ++d) c[d] = z[d] - mean;
    float var = dot20(c, c) * (1.0f / 20.0f);
    float rs = rsqrtf(var + EPS);
    float o[20];
#pragma unroll
    for (int d = 0; d < 20; ++d) o[d] = c[d] * rs * g2[d] + b2[d];

    float4* op = (float4*)(Out + (size_t)b * (S * D) + s * D);
#pragma unroll
    for (int i = 0; i < 5; ++i) {
      float4 t;
      t.x = o[4 * i + 0]; t.y = o[4 * i + 1]; t.z = o[4 * i + 2]; t.w = o[4 * i + 3];
      op[i] = t;
    }
  }
}

extern "C" void kernel_launch(void* const* d_in, const int* in_sizes, int n_in,
                              void* d_out, int out_size, void* d_ws, size_t ws_size,
                              hipStream_t stream) {
  const float* X  = (const float*)d_in[0];
  const float* Wq = (const float*)d_in[1];
  const float* bq = (const float*)d_in[2];
  const float* Wk = (const float*)d_in[3];
  const float* bk = (const float*)d_in[4];
  const float* Wv = (const float*)d_in[5];
  const float* bv = (const float*)d_in[6];
  const float* Wo = (const float*)d_in[7];
  const float* bo = (const float*)d_in[8];
  const float* g1 = (const float*)d_in[9];
  const float* b1 = (const float*)d_in[10];
  const float* W1 = (const float*)d_in[11];
  const float* W2 = (const float*)d_in[12];
  const float* g2 = (const float*)d_in[13];
  const float* b2 = (const float*)d_in[14];
  float* Out = (float*)d_out;
  float* ws = (float*)d_ws;

  prep_kernel<<<24, 512, 0, stream>>>(Wq, Wk, Wv, Wo, W1, ws);

  // 4 waves/block * 7 batch elements/wave = 28 batch elements per block
  int nblocks = (B_TOT + 27) / 28;
  encoder_kernel<<<nblocks, 256, 0, stream>>>(X, ws, bq, bk, bv, bo, g1, b1,
                                              W2, g2, b2, Out);
}

// Round 3
// 144.423 us; speedup vs baseline: 3.5258x; 2.5942x over previous
//
#include <hip/hip_runtime.h>

#define B_TOT 65536
#define S 9
#define D 20
#define H 4
#define DH 5
#define DFF 512
#define EPS 1e-5f

typedef short bf16x8 __attribute__((ext_vector_type(8)));
typedef float f32x4 __attribute__((ext_vector_type(4)));

// ws byte layout:
//   [0, 6400)       : WqT,WkT,WvT,WoT fp32 (4 * 400 floats)
//   [6400, 39168)   : PA1 bf16 [32 ftiles][64 lanes][8]  (W1^T A-fragments, k-padded 20->32)
//   [39168, 71936)  : PB2 bf16 [16 kk][2 ctile][64][8]   (W2 B-fragments, d-padded 20->32)
#define WS_WQT 0
#define WS_WKT 400
#define WS_WVT 800
#define WS_WOT 1200
#define WS_PA1_BYTE 6400
#define WS_PB2_BYTE 39168
#define PREP_TOTAL (1600 + 16384 + 16384)

__device__ __forceinline__ unsigned short f2bf(float f) {
  union { float f; unsigned u; } v; v.f = f;
  return (unsigned short)((v.u + 0x7fffu + ((v.u >> 16) & 1u)) >> 16);
}
__device__ __forceinline__ float bf2f(unsigned short h) {
  union { unsigned u; float f; } v; v.u = ((unsigned)h) << 16; return v.f;
}

__global__ void prep_kernel(const float* __restrict__ Wq, const float* __restrict__ Wk,
                            const float* __restrict__ Wv, const float* __restrict__ Wo,
                            const float* __restrict__ W1, const float* __restrict__ W2,
                            float* __restrict__ wsf) {
  int stride = gridDim.x * blockDim.x;
  unsigned short* P = (unsigned short*)((char*)wsf + WS_PA1_BYTE);
  for (int i = blockIdx.x * blockDim.x + threadIdx.x; i < PREP_TOTAL; i += stride) {
    if (i < 1600) {
      int mi = i / 400;
      int r = i % 400;
      int j = r / 20, kk = r % 20;  // WT[j][kk] = W[kk][j]
      const float* Wsrc = (mi == 0) ? Wq : (mi == 1) ? Wk : (mi == 2) ? Wv : Wo;
      wsf[i] = Wsrc[kk * 20 + j];
    } else {
      int j = i - 1600;
      unsigned short val;
      if (j < 16384) {
        // PA1[t][l][jj] = (k=8g+jj)<20 ? W1[k][t*16+cl] : 0
        int t = j >> 9, rem = j & 511;
        int l = rem >> 3, jj = rem & 7;
        int g = l >> 4, cl = l & 15;
        int k = 8 * g + jj;
        int f = t * 16 + cl;
        val = (k < 20) ? f2bf(W1[k * DFF + f]) : (unsigned short)0;
      } else {
        // PB2[pair=(kk*2+cc)][l][jj] = (d=cc*16+cl)<20 ? W2[kk*32+8g+jj][d] : 0
        int jj2 = j - 16384;
        int pair = jj2 >> 9, rem = jj2 & 511;
        int l = rem >> 3, jj = rem & 7;
        int g = l >> 4, cl = l & 15;
        int kk = pair >> 1, cc = pair & 1;
        int kg = kk * 32 + 8 * g + jj;
        int d = cc * 16 + cl;
        val = (d < 20) ? f2bf(W2[kg * 20 + d]) : (unsigned short)0;
      }
      P[j] = val;
    }
  }
}

__device__ __forceinline__ float dot20(const float* __restrict__ w, const float* x) {
  float p0 = w[0] * x[0], p1 = w[1] * x[1], p2 = w[2] * x[2], p3 = w[3] * x[3];
#pragma unroll
  for (int k = 4; k < 20; k += 4) {
    p0 += w[k] * x[k];
    p1 += w[k + 1] * x[k + 1];
    p2 += w[k + 2] * x[k + 2];
    p3 += w[k + 3] * x[k + 3];
  }
  return (p0 + p1) + (p2 + p3);
}

__device__ __forceinline__ float sum20(const float* a) {
  float p0 = a[0] + a[4], p1 = a[1] + a[5], p2 = a[2] + a[6], p3 = a[3] + a[7];
#pragma unroll
  for (int k = 8; k < 20; k += 4) {
    p0 += a[k]; p1 += a[k + 1]; p2 += a[k + 2]; p3 += a[k + 3];
  }
  return (p0 + p1) + (p2 + p3);
}

// LDS layout per block (44736 B total, regions union across phases):
//   km : fp32 [4][7][9][20] at 0       (20160 B)  -- K, then merged-ctx; dead after mrow read
//   vv : fp32 [4][7][9][20] at 20160   (20160 B)  -- V; dead after ctx
//   Yl : bf16 [4][64][48]   at 20160   (24576 B)  -- overlaps vv (written post-barrier)
//   Hl : bf16 [4][16][136]  at 0       (17408 B)  -- overlaps km (written post-barrier)
__global__ __launch_bounds__(256, 3) void encoder_kernel(
    const float* __restrict__ X, const float* __restrict__ ws,
    const float* __restrict__ bq, const float* __restrict__ bk,
    const float* __restrict__ bv, const float* __restrict__ bo,
    const float* __restrict__ g1, const float* __restrict__ b1,
    const float* __restrict__ g2, const float* __restrict__ b2,
    float* __restrict__ Out) {
  __shared__ __align__(16) char smem[44736];

  const float* WqT = ws + WS_WQT;
  const float* WkT = ws + WS_WKT;
  const float* WvT = ws + WS_WVT;
  const float* WoT = ws + WS_WOT;
  const unsigned short* PA1 = (const unsigned short*)((const char*)ws + WS_PA1_BYTE);
  const unsigned short* PB2 = (const unsigned short*)((const char*)ws + WS_PB2_BYTE);

  const int tid = threadIdx.x;
  const int wv = tid >> 6;
  const int lane = tid & 63;
  const int bl = lane / 9;       // 0..7 (7 == pad lane 63)
  const int s = lane - bl * 9;
  const long wb = (long)blockIdx.x * 4 + wv;   // wave index
  const long bb = wb * 7 + bl;                 // batch element
  const bool active = (bl < 7) && (bb < B_TOT);

  float* km = (float*)(smem) + wv * (7 * 9 * 20);
  float* vvp = (float*)(smem + 20160) + wv * (7 * 9 * 20);
  unsigned short* Yl = (unsigned short*)(smem + 20160) + wv * (64 * 48);
  unsigned short* Hl = (unsigned short*)(smem) + wv * (16 * 136);

  float x[20], q[20], ctx[20], y[20];

  // ---------------- Phase A: QKV + attention + Wo + LN1 (row-per-lane) -------
  if (active) {
    const float4* xr = (const float4*)(X + bb * (S * D) + s * D);
#pragma unroll
    for (int i = 0; i < 5; ++i) {
      float4 t = xr[i];
      x[4 * i + 0] = t.x; x[4 * i + 1] = t.y; x[4 * i + 2] = t.z; x[4 * i + 3] = t.w;
    }
#pragma unroll
    for (int j = 0; j < 20; ++j) q[j] = dot20(WqT + 20 * j, x) + bq[j];
#pragma unroll
    for (int j = 0; j < 20; ++j) km[(bl * 9 + s) * 20 + j] = dot20(WkT + 20 * j, x) + bk[j];
#pragma unroll
    for (int j = 0; j < 20; ++j) vvp[(bl * 9 + s) * 20 + j] = dot20(WvT + 20 * j, x) + bv[j];
  }
  // per-wave-private LDS: compiler-inserted lgkmcnt orders write->read within wave

  if (active) {
#pragma unroll
    for (int h = 0; h < H; ++h) {
      float sc[S];
#pragma unroll
      for (int t = 0; t < S; ++t) {
        const float* kk = km + (bl * 9 + t) * 20 + h * DH;
        float d0 = q[h * DH + 0] * kk[0] + q[h * DH + 1] * kk[1];
        float d1 = q[h * DH + 2] * kk[2] + q[h * DH + 3] * kk[3];
        sc[t] = (d0 + d1 + q[h * DH + 4] * kk[4]) * (1.0f / 3.0f);
      }
      float mx = sc[0];
#pragma unroll
      for (int t = 1; t < S; ++t) mx = fmaxf(mx, sc[t]);
      float e[S];
      float sum = 0.f;
#pragma unroll
      for (int t = 0; t < S; ++t) { e[t] = __expf(sc[t] - mx); sum += e[t]; }
      float inv = 1.0f / sum;
#pragma unroll
      for (int dh = 0; dh < DH; ++dh) {
        float c = 0.f;
#pragma unroll
        for (int t = 0; t < S; ++t) c += e[t] * vvp[(bl * 9 + t) * 20 + h * DH + dh];
        ctx[h * DH + dh] = c * inv;
      }
    }
    // merged write (transpose quirk): merged[s][h*5+dh] laid as h*45 + dh*9 + s
    float* mbase = km + bl * 180;
#pragma unroll
    for (int h = 0; h < H; ++h)
#pragma unroll
      for (int dh = 0; dh < DH; ++dh)
        mbase[h * 45 + dh * 9 + s] = ctx[h * DH + dh];
  }

  if (active) {
    float mrow[20];
#pragma unroll
    for (int j = 0; j < 20; ++j) mrow[j] = km[(bl * 9 + s) * 20 + j];
    float ao[20];
#pragma unroll
    for (int d = 0; d < 20; ++d) ao[d] = dot20(WoT + 20 * d, mrow) + bo[d] + x[d];
    float mean = sum20(ao) * (1.0f / 20.0f);
    float c[20];
#pragma unroll
    for (int d = 0; d < 20; ++d) c[d] = ao[d] - mean;
    float var = dot20(c, c) * (1.0f / 20.0f);
    float rs = rsqrtf(var + EPS);
#pragma unroll
    for (int d = 0; d < 20; ++d) y[d] = c[d] * rs * g1[d] + b1[d];
  } else {
#pragma unroll
    for (int d = 0; d < 20; ++d) y[d] = 0.f;
  }

  __syncthreads();  // A->B: all km/vv reads complete block-wide before Y/H overwrite

  // ---------------- Phase B: FFN via bf16 MFMA -------------------------------
  // Write this lane's y row to Y LDS as bf16 (cols 20..31 zeroed = K-pad)
  {
    const int row = bl * 9 + s;  // 0..63, distinct per lane
    unsigned u[16];
#pragma unroll
    for (int i = 0; i < 10; ++i)
      u[i] = (unsigned)f2bf(y[2 * i]) | ((unsigned)f2bf(y[2 * i + 1]) << 16);
#pragma unroll
    for (int i = 10; i < 16; ++i) u[i] = 0u;
    uint4* dst = (uint4*)(Yl + row * 48);
    dst[0] = make_uint4(u[0], u[1], u[2], u[3]);
    dst[1] = make_uint4(u[4], u[5], u[6], u[7]);
    dst[2] = make_uint4(u[8], u[9], u[10], u[11]);
    dst[3] = make_uint4(u[12], u[13], u[14], u[15]);
  }

  const int cl = lane & 15;
  const int g = lane >> 4;

  // Y^T B-fragments: lane holds Y[rt*16+cl][8g..8g+7]  (one per row-tile)
  bf16x8 ytf[4];
#pragma unroll
  for (int rt = 0; rt < 4; ++rt)
    ytf[rt] = *(const bf16x8*)(Yl + (rt * 16 + cl) * 48 + g * 8);

  f32x4 acc[4][2];
#pragma unroll
  for (int rt = 0; rt < 4; ++rt) {
    acc[rt][0] = (f32x4){0.f, 0.f, 0.f, 0.f};
    acc[rt][1] = (f32x4){0.f, 0.f, 0.f, 0.f};
  }

  for (int ch = 0; ch < 4; ++ch) {
    // weight fragments for this 128-wide DFF chunk (reused over 4 row-tiles)
    bf16x8 a1[8], b2[8];
#pragma unroll
    for (int i = 0; i < 8; ++i)
      a1[i] = *(const bf16x8*)(PA1 + ((ch * 8 + i) * 64 + lane) * 8);
#pragma unroll
    for (int i = 0; i < 8; ++i)
      b2[i] = *(const bf16x8*)(PB2 + ((ch * 8 + i) * 64 + lane) * 8);

#pragma unroll
    for (int rt = 0; rt < 4; ++rt) {
      // FFN1 (swapped): D' = W1T_tile[16f x 32d] * Y^T[32d x 16r] -> H^T frag
      // lane holds H[row=cl][f = i*16 + 4g + reg] -> 4 consecutive f -> b64 write
#pragma unroll
      for (int i = 0; i < 8; ++i) {
        f32x4 d = __builtin_amdgcn_mfma_f32_16x16x32_bf16(
            a1[i], ytf[rt], (f32x4){0.f, 0.f, 0.f, 0.f}, 0, 0, 0);
        unsigned lo = (unsigned)f2bf(fmaxf(d[0], 0.f)) |
                      ((unsigned)f2bf(fmaxf(d[1], 0.f)) << 16);
        unsigned hi = (unsigned)f2bf(fmaxf(d[2], 0.f)) |
                      ((unsigned)f2bf(fmaxf(d[3], 0.f)) << 16);
        *(uint2*)(Hl + cl * 136 + i * 16 + 4 * g) = make_uint2(lo, hi);
      }
      // FFN2: acc += H_tile[16r x 32f] * W2_chunk[32f x 16d]  (2 d-tiles)
#pragma unroll
      for (int q2 = 0; q2 < 4; ++q2) {
        bf16x8 hf = *(const bf16x8*)(Hl + cl * 136 + q2 * 32 + g * 8);
        acc[rt][0] = __builtin_amdgcn_mfma_f32_16x16x32_bf16(hf, b2[2 * q2 + 0], acc[rt][0], 0, 0, 0);
        acc[rt][1] = __builtin_amdgcn_mfma_f32_16x16x32_bf16(hf, b2[2 * q2 + 1], acc[rt][1], 0, 0, 0);
      }
    }
  }

  // ---------------- LN2 in fragment space + store ----------------------------
  const float gg0 = g2[cl], bb0 = b2[cl];
  const float gg1 = (cl < 4) ? g2[16 + cl] : 0.f;
  const float bb1 = (cl < 4) ? b2[16 + cl] : 0.f;
  const long wrbase = wb * 63;
  const long total_rows = (long)B_TOT * S;

#pragma unroll
  for (int rt = 0; rt < 4; ++rt) {
#pragma unroll
    for (int r = 0; r < 4; ++r) {
      const int row = rt * 16 + 4 * g + r;
      float y0 = bf2f(Yl[row * 48 + cl]);
      float y1 = (cl < 4) ? bf2f(Yl[row * 48 + 16 + cl]) : 0.f;
      float z0 = acc[rt][0][r] + y0;
      float z1 = acc[rt][1][r] + y1;  // valid only cl<4 (cols 16..19)
      float t = z0 + ((cl < 4) ? z1 : 0.f);
      t += __shfl_xor(t, 1, 16);
      t += __shfl_xor(t, 2, 16);
      t += __shfl_xor(t, 4, 16);
      t += __shfl_xor(t, 8, 16);
      float mean = t * (1.0f / 20.0f);
      float c0 = z0 - mean, c1 = z1 - mean;
      float vt = c0 * c0 + ((cl < 4) ? c1 * c1 : 0.f);
      vt += __shfl_xor(vt, 1, 16);
      vt += __shfl_xor(vt, 2, 16);
      vt += __shfl_xor(vt, 4, 16);
      vt += __shfl_xor(vt, 8, 16);
      float rs = rsqrtf(vt * (1.0f / 20.0f) + EPS);
      const long grow = wrbase + row;
      if (row < 63 && grow < total_rows) {
        Out[grow * 20 + cl] = c0 * rs * gg0 + bb0;
        if (cl < 4) Out[grow * 20 + 16 + cl] = c1 * rs * gg1 + bb1;
      }
    }
  }
}

extern "C" void kernel_launch(void* const* d_in, const int* in_sizes, int n_in,
                              void* d_out, int out_size, void* d_ws, size_t ws_size,
                              hipStream_t stream) {
  const float* X  = (const float*)d_in[0];
  const float* Wq = (const float*)d_in[1];
  const float* bq = (const float*)d_in[2];
  const float* Wk = (const float*)d_in[3];
  const float* bk = (const float*)d_in[4];
  const float* Wv = (const float*)d_in[5];
  const float* bv = (const float*)d_in[6];
  const float* Wo = (const float*)d_in[7];
  const float* bo = (const float*)d_in[8];
  const float* g1 = (const float*)d_in[9];
  const float* b1 = (const float*)d_in[10];
  const float* W1 = (const float*)d_in[11];
  const float* W2 = (const float*)d_in[12];
  const float* g2 = (const float*)d_in[13];
  const float* b2 = (const float*)d_in[14];
  float* Out = (float*)d_out;
  float* ws = (float*)d_ws;

  prep_kernel<<<135, 256, 0, stream>>>(Wq, Wk, Wv, Wo, W1, W2, ws);

  int nblocks = (B_TOT + 27) / 28;  // 4 waves/block * 7 batch elems/wave
  encoder_kernel<<<nblocks, 256, 0, stream>>>(X, ws, bq, bk, bv, bo, g1, b1,
                                              g2, b2, Out);
}

// Round 5
// 125.508 us; speedup vs baseline: 4.0572x; 1.1507x over previous
//
#include <hip/hip_runtime.h>
#include <hip/hip_bf16.h>

#define B_TOT 65536
#define S 9
#define D 20
#define DFF 512
#define EPS 1e-5f

typedef short bf16x8 __attribute__((ext_vector_type(8)));
typedef float f32x4 __attribute__((ext_vector_type(4)));

// ws byte layout:
//   [0, 6400)       : WqT,WkT,WvT,WoT fp32 (4 * 400 floats)
//   [6400, 39168)   : PA1 bf16 [32 frags][64 lanes][8]  (W1 A-frags, PERMUTED rows:
//                     frag=(ch*4+q2)*2+p holds A[row=cl][k=d] = W1[d][f],
//                     f = ch*128+q2*32+8*(cl>>2)+4*p+(cl&3)  -> FFN1 D-frag == FFN2 A-frag)
//   [39168, 71936)  : PB2 bf16 [16 kk][2 cc][64][8]  (W2 B-frags, d-padded 20->32)
#define WS_PA1_BYTE 6400
#define WS_PB2_BYTE 39168
#define PREP_TOTAL (1600 + 16384 + 16384)

__device__ __forceinline__ unsigned short f2bf(float f) {
  union { __hip_bfloat16 h; unsigned short u; } v;
  v.h = __float2bfloat16(f);
  return v.u;
}
__device__ __forceinline__ float bf2f(unsigned short h) {
  union { unsigned u; float f; } v; v.u = ((unsigned)h) << 16; return v.f;
}
__device__ __forceinline__ unsigned cvt2(float a, float b) {
  union { __hip_bfloat162 h; unsigned u; } v;
  v.h = __float22bfloat162_rn(make_float2(a, b));
  return v.u;
}

__global__ void prep_kernel(const float* __restrict__ Wq, const float* __restrict__ Wk,
                            const float* __restrict__ Wv, const float* __restrict__ Wo,
                            const float* __restrict__ W1, const float* __restrict__ W2,
                            float* __restrict__ wsf) {
  int stride = gridDim.x * blockDim.x;
  unsigned short* P = (unsigned short*)((char*)wsf + WS_PA1_BYTE);
  for (int i = blockIdx.x * blockDim.x + threadIdx.x; i < PREP_TOTAL; i += stride) {
    if (i < 1600) {
      int mi = i / 400;
      int r = i % 400;
      int j = r / 20, kk = r % 20;  // WT[j][kk] = W[kk][j]
      const float* Wsrc = (mi == 0) ? Wq : (mi == 1) ? Wk : (mi == 2) ? Wv : Wo;
      wsf[i] = Wsrc[kk * 20 + j];
    } else {
      int j = i - 1600;
      unsigned short val;
      if (j < 16384) {
        // PA1: permuted W1 A-fragments
        int frag = j >> 9, rem = j & 511;
        int l = rem >> 3, jj = rem & 7;
        int p = frag & 1, q2 = (frag >> 1) & 3, ch = frag >> 3;
        int g2 = l >> 4, cl2 = l & 15;
        int k = 8 * g2 + jj;                                       // d-dim (pad 20->32)
        int f = ch * 128 + q2 * 32 + 8 * (cl2 >> 2) + 4 * p + (cl2 & 3);
        val = (k < 20) ? f2bf(W1[k * DFF + f]) : (unsigned short)0;
      } else {
        // PB2[pair=(kk*2+cc)][l][jj] = (d=cc*16+cl)<20 ? W2[kk*32+8g+jj][d] : 0
        int jj2 = j - 16384;
        int pair = jj2 >> 9, rem = jj2 & 511;
        int l = rem >> 3, jj = rem & 7;
        int g = l >> 4, cl = l & 15;
        int kk = pair >> 1, cc = pair & 1;
        int kg = kk * 32 + 8 * g + jj;
        int d = cc * 16 + cl;
        val = (d < 20) ? f2bf(W2[kg * 20 + d]) : (unsigned short)0;
      }
      P[j] = val;
    }
  }
}

__device__ __forceinline__ float dot20(const float* __restrict__ w, const float* x) {
  float p0 = w[0] * x[0], p1 = w[1] * x[1], p2 = w[2] * x[2], p3 = w[3] * x[3];
#pragma unroll
  for (int k = 4; k < 20; k += 4) {
    p0 += w[k] * x[k];
    p1 += w[k + 1] * x[k + 1];
    p2 += w[k + 2] * x[k + 2];
    p3 += w[k + 3] * x[k + 3];
  }
  return (p0 + p1) + (p2 + p3);
}

__device__ __forceinline__ float sum20(const float* a) {
  float p0 = a[0] + a[4], p1 = a[1] + a[5], p2 = a[2] + a[6], p3 = a[3] + a[7];
#pragma unroll
  for (int k = 8; k < 20; k += 4) {
    p0 += a[k]; p1 += a[k + 1]; p2 += a[k + 2]; p3 += a[k + 3];
  }
  return (p0 + p1) + (p2 + p3);
}

// Per-wave LDS slab (10080 B, all regions wave-private -> NO __syncthreads):
//   kv rows: KVB(r) = r*160, r = bl*9+s = lane (k dw 0..19, v dw 20..39). LINEAR —
//            no stagger: staggering without allocated pad overlapped rows 15/16 etc
//            (round-4 bug: same-instruction two-lane store race).
//   merged : fp32 flat [7][180] at slab+0 (overlays dead-K after all k/v reads)
//   Yl     : bf16 rows YB(r) = r*96 at slab+0 (overlays all, phase B; 64B write < 96B stride)
// Cross-type overlays (float vs uint/short) are fenced with asm memory clobbers:
// same-wave LDS ops execute in order, but IR-level TBAA could otherwise reorder.
#define SLAB_BYTES 10080
#define KVB(r) ((r) * 160)
#define YB(r) ((r) * 96)

__global__ __launch_bounds__(256, 4) void encoder_kernel(
    const float* __restrict__ X, const float* __restrict__ ws,
    const float* __restrict__ bq, const float* __restrict__ bk,
    const float* __restrict__ bv, const float* __restrict__ bo,
    const float* __restrict__ g1, const float* __restrict__ b1,
    const float* __restrict__ g2, const float* __restrict__ b2,
    float* __restrict__ Out) {
  __shared__ __align__(16) char smem[4 * SLAB_BYTES];

  const float* WqT = ws + 0;
  const float* WkT = ws + 400;
  const float* WvT = ws + 800;
  const float* WoT = ws + 1200;
  const unsigned short* PA1 = (const unsigned short*)((const char*)ws + WS_PA1_BYTE);
  const unsigned short* PB2 = (const unsigned short*)((const char*)ws + WS_PB2_BYTE);

  const int tid = threadIdx.x;
  const int wv = tid >> 6;
  const int lane = tid & 63;
  const int bl = lane / 9;       // 0..7 (7 == pad lane 63)
  const int s = lane - bl * 9;
  const long wb = (long)blockIdx.x * 4 + wv;
  const long bb = wb * 7 + bl;
  const bool active = (bl < 7) && (bb < B_TOT);

  char* slab = smem + wv * SLAB_BYTES;
  const int rowA = bl * 9 + s;   // == lane

  float x[20], q[20], y[20];

  // ---------------- Phase A: QKV (VALU, s_load weights) ----------------------
  if (active) {
    const float4* xr = (const float4*)(X + bb * (S * D) + s * D);
#pragma unroll
    for (int i = 0; i < 5; ++i) {
      float4 t = xr[i];
      x[4 * i + 0] = t.x; x[4 * i + 1] = t.y; x[4 * i + 2] = t.z; x[4 * i + 3] = t.w;
    }
#pragma unroll
    for (int j = 0; j < 20; ++j) q[j] = dot20(WqT + 20 * j, x) + bq[j];
    float kr[20], vr[20];
#pragma unroll
    for (int j = 0; j < 20; ++j) kr[j] = dot20(WkT + 20 * j, x) + bk[j];
#pragma unroll
    for (int j = 0; j < 20; ++j) vr[j] = dot20(WvT + 20 * j, x) + bv[j];
    float4* kw = (float4*)(slab + KVB(rowA));
#pragma unroll
    for (int i = 0; i < 5; ++i)
      kw[i] = make_float4(kr[4 * i], kr[4 * i + 1], kr[4 * i + 2], kr[4 * i + 3]);
#pragma unroll
    for (int i = 0; i < 5; ++i)
      kw[5 + i] = make_float4(vr[4 * i], vr[4 * i + 1], vr[4 * i + 2], vr[4 * i + 3]);
  }

  // ---------------- attention: t-outer, wide row reads -----------------------
  if (active) {
    float sc[4][9];
#pragma unroll
    for (int t = 0; t < 9; ++t) {
      const float4* rp = (const float4*)(slab + KVB(bl * 9 + t));
      float kt[20];
#pragma unroll
      for (int i = 0; i < 5; ++i) {
        float4 c = rp[i];
        kt[4 * i] = c.x; kt[4 * i + 1] = c.y; kt[4 * i + 2] = c.z; kt[4 * i + 3] = c.w;
      }
#pragma unroll
      for (int h = 0; h < 4; ++h) {
        float d0 = q[h * 5 + 0] * kt[h * 5 + 0] + q[h * 5 + 1] * kt[h * 5 + 1];
        float d1 = q[h * 5 + 2] * kt[h * 5 + 2] + q[h * 5 + 3] * kt[h * 5 + 3];
        sc[h][t] = d0 + d1 + q[h * 5 + 4] * kt[h * 5 + 4];
      }
    }
    float inv[4];
#pragma unroll
    for (int h = 0; h < 4; ++h) {
      float mx = sc[h][0];
#pragma unroll
      for (int t = 1; t < 9; ++t) mx = fmaxf(mx, sc[h][t]);
      float sum = 0.f;
#pragma unroll
      for (int t = 0; t < 9; ++t) {
        sc[h][t] = __expf((sc[h][t] - mx) * (1.0f / 3.0f));
        sum += sc[h][t];
      }
      inv[h] = 1.0f / sum;
    }
    float ctx[20];
#pragma unroll
    for (int j = 0; j < 20; ++j) ctx[j] = 0.f;
#pragma unroll
    for (int t = 0; t < 9; ++t) {
      const float4* rp = (const float4*)(slab + KVB(bl * 9 + t));
      float vt[20];
#pragma unroll
      for (int i = 0; i < 5; ++i) {
        float4 c = rp[5 + i];
        vt[4 * i] = c.x; vt[4 * i + 1] = c.y; vt[4 * i + 2] = c.z; vt[4 * i + 3] = c.w;
      }
#pragma unroll
      for (int j = 0; j < 20; ++j) ctx[j] += sc[j / 5][t] * vt[j];
    }
#pragma unroll
    for (int j = 0; j < 20; ++j) ctx[j] *= inv[j / 5];

    asm volatile("" ::: "memory");      // IR fence: v-reads before merged overlay
    __builtin_amdgcn_sched_barrier(0);  // sched fence
    // merged (transpose quirk): flat linear = h*45 + dh*9 + s within [9][20]
    float* mg = (float*)slab;
#pragma unroll
    for (int h = 0; h < 4; ++h)
#pragma unroll
      for (int dh = 0; dh < 5; ++dh)
        mg[bl * 180 + h * 45 + dh * 9 + s] = ctx[h * 5 + dh];
  }

  // ---------------- Wo + LN1 -------------------------------------------------
  if (active) {
    const float* mg = (const float*)slab;
    float mrow[20];
    const float4* mr = (const float4*)(mg + bl * 180 + s * 20);
#pragma unroll
    for (int i = 0; i < 5; ++i) {
      float4 c = mr[i];
      mrow[4 * i] = c.x; mrow[4 * i + 1] = c.y; mrow[4 * i + 2] = c.z; mrow[4 * i + 3] = c.w;
    }
    float ao[20];
#pragma unroll
    for (int d = 0; d < 20; ++d) ao[d] = dot20(WoT + 20 * d, mrow) + bo[d] + x[d];
    float mean = sum20(ao) * (1.0f / 20.0f);
    float c[20];
#pragma unroll
    for (int d = 0; d < 20; ++d) c[d] = ao[d] - mean;
    float var = dot20(c, c) * (1.0f / 20.0f);
    float rs = rsqrtf(var + EPS);
#pragma unroll
    for (int d = 0; d < 20; ++d) y[d] = c[d] * rs * g1[d] + b1[d];
  } else {
#pragma unroll
    for (int d = 0; d < 20; ++d) y[d] = 0.f;
  }

  asm volatile("" ::: "memory");      // IR fence: merged reads before Yl overlay
  __builtin_amdgcn_sched_barrier(0);

  // ---------------- Phase B: FFN via MFMA (register-resident H) --------------
  {
    unsigned u[10];
#pragma unroll
    for (int i = 0; i < 10; ++i) u[i] = cvt2(y[2 * i], y[2 * i + 1]);
    uint4* dst = (uint4*)(slab + YB(rowA));
    dst[0] = make_uint4(u[0], u[1], u[2], u[3]);
    dst[1] = make_uint4(u[4], u[5], u[6], u[7]);
    dst[2] = make_uint4(u[8], u[9], 0u, 0u);
    dst[3] = make_uint4(0u, 0u, 0u, 0u);
  }
  asm volatile("" ::: "memory");      // IR fence: Yl writes before cross-lane reads
  __builtin_amdgcn_sched_barrier(0);

  const int cl = lane & 15;
  const int g = lane >> 4;

  bf16x8 ytf[4];
#pragma unroll
  for (int rt = 0; rt < 4; ++rt)
    ytf[rt] = *(const bf16x8*)(slab + YB(rt * 16 + cl) + g * 16);

  const f32x4 zero4 = {0.f, 0.f, 0.f, 0.f};
  f32x4 acc[4][2];
#pragma unroll
  for (int rt = 0; rt < 4; ++rt) { acc[rt][0] = zero4; acc[rt][1] = zero4; }

  for (int ch = 0; ch < 4; ++ch) {
#pragma unroll
    for (int q2 = 0; q2 < 4; ++q2) {
      const int fb = ch * 8 + q2 * 2;
      bf16x8 aw0 = *(const bf16x8*)(PA1 + (size_t)(fb * 64 + lane) * 8);
      bf16x8 aw1 = *(const bf16x8*)(PA1 + (size_t)((fb + 1) * 64 + lane) * 8);
      bf16x8 bw0 = *(const bf16x8*)(PB2 + (size_t)(fb * 64 + lane) * 8);
      bf16x8 bw1 = *(const bf16x8*)(PB2 + (size_t)((fb + 1) * 64 + lane) * 8);
#pragma unroll
      for (int rt = 0; rt < 4; ++rt) {
        f32x4 d0 = __builtin_amdgcn_mfma_f32_16x16x32_bf16(aw0, ytf[rt], zero4, 0, 0, 0);
        f32x4 d1 = __builtin_amdgcn_mfma_f32_16x16x32_bf16(aw1, ytf[rt], zero4, 0, 0, 0);
        union { bf16x8 v; unsigned uu[4]; } af;
        af.uu[0] = cvt2(fmaxf(d0[0], 0.f), fmaxf(d0[1], 0.f));
        af.uu[1] = cvt2(fmaxf(d0[2], 0.f), fmaxf(d0[3], 0.f));
        af.uu[2] = cvt2(fmaxf(d1[0], 0.f), fmaxf(d1[1], 0.f));
        af.uu[3] = cvt2(fmaxf(d1[2], 0.f), fmaxf(d1[3], 0.f));
        acc[rt][0] = __builtin_amdgcn_mfma_f32_16x16x32_bf16(af.v, bw0, acc[rt][0], 0, 0, 0);
        acc[rt][1] = __builtin_amdgcn_mfma_f32_16x16x32_bf16(af.v, bw1, acc[rt][1], 0, 0, 0);
      }
    }
  }

  // ---------------- LN2 in fragment space + store ----------------------------
  const float gg0 = g2[cl], bb0 = b2[cl];
  const float gg1 = (cl < 4) ? g2[16 + cl] : 0.f;
  const float bb1 = (cl < 4) ? b2[16 + cl] : 0.f;
  const long wrbase = wb * 63;
  const long total_rows = (long)B_TOT * S;

#pragma unroll
  for (int rt = 0; rt < 4; ++rt) {
#pragma unroll
    for (int r = 0; r < 4; ++r) {
      const int rrow = rt * 16 + 4 * g + r;
      float y0 = bf2f(*(const unsigned short*)(slab + YB(rrow) + cl * 2));
      float y1 = (cl < 4) ? bf2f(*(const unsigned short*)(slab + YB(rrow) + 32 + cl * 2)) : 0.f;
      float z0 = acc[rt][0][r] + y0;
      float z1 = acc[rt][1][r] + y1;
      float t = z0 + ((cl < 4) ? z1 : 0.f);
      t += __shfl_xor(t, 1, 16);
      t += __shfl_xor(t, 2, 16);
      t += __shfl_xor(t, 4, 16);
      t += __shfl_xor(t, 8, 16);
      float mean = t * (1.0f / 20.0f);
      float c0 = z0 - mean, c1 = z1 - mean;
      float vt = c0 * c0 + ((cl < 4) ? c1 * c1 : 0.f);
      vt += __shfl_xor(vt, 1, 16);
      vt += __shfl_xor(vt, 2, 16);
      vt += __shfl_xor(vt, 4, 16);
      vt += __shfl_xor(vt, 8, 16);
      float rs = rsqrtf(vt * (1.0f / 20.0f) + EPS);
      const long grow = wrbase + rrow;
      if (rrow < 63 && grow < total_rows) {
        Out[grow * 20 + cl] = c0 * rs * gg0 + bb0;
        if (cl < 4) Out[grow * 20 + 16 + cl] = c1 * rs * gg1 + bb1;
      }
    }
  }
}

extern "C" void kernel_launch(void* const* d_in, const int* in_sizes, int n_in,
                              void* d_out, int out_size, void* d_ws, size_t ws_size,
                              hipStream_t stream) {
  const float* X  = (const float*)d_in[0];
  const float* Wq = (const float*)d_in[1];
  const float* bq = (const float*)d_in[2];
  const float* Wk = (const float*)d_in[3];
  const float* bk = (const float*)d_in[4];
  const float* Wv = (const float*)d_in[5];
  const float* bv = (const float*)d_in[6];
  const float* Wo = (const float*)d_in[7];
  const float* bo = (const float*)d_in[8];
  const float* g1 = (const float*)d_in[9];
  const float* b1 = (const float*)d_in[10];
  const float* W1 = (const float*)d_in[11];
  const float* W2 = (const float*)d_in[12];
  const float* g2 = (const float*)d_in[13];
  const float* b2 = (const float*)d_in[14];
  float* Out = (float*)d_out;
  float* ws = (float*)d_ws;

  prep_kernel<<<135, 256, 0, stream>>>(Wq, Wk, Wv, Wo, W1, W2, ws);

  int nblocks = (B_TOT + 27) / 28;  // 4 waves/block * 7 batch elems/wave
  encoder_kernel<<<nblocks, 256, 0, stream>>>(X, ws, bq, bk, bv, bo, g1, b1,
                                              g2, b2, Out);
}